// Round 8
// baseline (947.334 us; speedup 1.0000x reference)
//
#include <hip/hip_runtime.h>
#include <float.h>
#include <limits.h>

// Problem constants
#define BB 16384   // batch rows
#define DIN 1024   // encoder input dim
#define CB 512     // codebook dim
#define KC 1024    // codewords per layer
#define NL 4       // layers

// Refine margin: must exceed stage1 bf16-split noise (~1e-3). ~10x slack.
#define DELTA 0.01f

typedef __attribute__((ext_vector_type(8))) short short8;
typedef __attribute__((ext_vector_type(4))) float f32x4;

__device__ __forceinline__ unsigned short f2bf(float f) {
  unsigned int u = __float_as_uint(f);
  u = u + 0x7fffu + ((u >> 16) & 1u);
  return (unsigned short)(u >> 16);
}
__device__ __forceinline__ float bf2f(unsigned short h) {
  return __uint_as_float(((unsigned int)h) << 16);
}

// Staged layout (shorts) for matrix M[rows][512]:
//   off(row,k) = ((row>>4)*16 + (k>>5))*512 + (((k>>3)&3)*16 + (row&15))*8 + (k&7)
// = MFMA A/B fragment lane image; staging = contiguous 1KB loads.
__device__ __forceinline__ size_t staged_off(int row, int k) {
  return ((size_t)(row >> 4) * 16 + (k >> 5)) * 512 +
         (((k >> 3) & 3) * 16 + (row & 15)) * 8 + (k & 7);
}

// ---------------------------------------------------------------------------
// Split codebooks into bf16 hi/lo, written in staged layout.
// ---------------------------------------------------------------------------
__global__ __launch_bounds__(256) void cbsplit_kernel(
    const float* __restrict__ cbs, unsigned short* __restrict__ Chi,
    unsigned short* __restrict__ Clo) {
  int g = (blockIdx.x * 256 + threadIdx.x) * 4;  // flat over NL*KC*CB
  int k = g & (CB - 1);
  int lr = g >> 9;
  int layer = lr >> 10, row = lr & (KC - 1);
  float4 v = *(const float4*)(cbs + g);
  float vv[4] = {v.x, v.y, v.z, v.w};
  unsigned short hh[4], ll[4];
#pragma unroll
  for (int i = 0; i < 4; ++i) {
    hh[i] = f2bf(vv[i]);
    ll[i] = f2bf(vv[i] - bf2f(hh[i]));
  }
  size_t off = (size_t)layer * (KC / 16) * 8192 + staged_off(row, k);
  *(ushort4*)(Chi + off) = make_ushort4(hh[0], hh[1], hh[2], hh[3]);
  *(ushort4*)(Clo + off) = make_ushort4(ll[0], ll[1], ll[2], ll[3]);
}

// ---------------------------------------------------------------------------
// cnorm[l*KC+k] = ||codebooks[l][k]||^2, fp64 (refine) + fp32 (stage1)
// ---------------------------------------------------------------------------
__global__ __launch_bounds__(256) void cnorm_kernel(
    const float* __restrict__ cbs, double* __restrict__ cnorm,
    float* __restrict__ cnormF) {
  int gw = (blockIdx.x * blockDim.x + threadIdx.x) >> 6;
  int lane = threadIdx.x & 63;
  if (gw >= NL * KC) return;
  const float* row = cbs + (size_t)gw * CB;
  double s = 0.0;
  for (int i = lane; i < CB; i += 64) {
    double v = (double)row[i];
    s += v * v;
  }
#pragma unroll
  for (int off = 32; off > 0; off >>= 1)
    s += __shfl_down(s, off, 64);
  if (lane == 0) { cnorm[gw] = s; cnormF[gw] = (float)s; }
}

// ---------------------------------------------------------------------------
// Encoder GEMM: R = X @ W + b, fp64 accumulation, fp64-in-LDS.
// 128x64 tile, 4x8 per thread. LDS tiles pre-converted to fp64 during
// staging, so the inner loop is pure ds_read_b128 + v_fma_f64 (no cvt).
// Per-element k-ascending accumulation order identical to R5/R6 ->
// bitwise-identical R -> identical downstream decisions.
// ---------------------------------------------------------------------------
__global__ __launch_bounds__(256, 4) void enc_gemm(
    const float* __restrict__ X, const float* __restrict__ W,
    const float* __restrict__ bias, float* __restrict__ R,
    unsigned short* __restrict__ Rhi, unsigned short* __restrict__ Rlo) {
  __shared__ double As64[16][130];  // [kk][m], pad 130 (1040B rows, 16B-aligned)
  __shared__ double Bs64[16][66];   // [kk][n], pad 66  (528B rows, 16B-aligned)
  int tid = threadIdx.x;
  int tx = tid & 7, ty = tid >> 3;  // 8 col-groups x 32 row-groups
  int g = blockIdx.x;
  int rb = (g & 7) + ((g >> 6) << 3);  // 8 col-blocks of rb share an XCD
  int cb8 = (g >> 3) & 7;
  int row0 = rb * 128, col0 = cb8 * 64;

  int sm = tid >> 1, skb = (tid & 1) * 8;   // A staging: row, k-base
  int bkk = tid >> 4, bn = (tid & 15) * 4;  // B staging: kk, col

  double acc[4][8] = {};
  for (int k0 = 0; k0 < DIN; k0 += 16) {
    float4 x0 = *(const float4*)(X + (size_t)(row0 + sm) * DIN + k0 + skb);
    float4 x1 = *(const float4*)(X + (size_t)(row0 + sm) * DIN + k0 + skb + 4);
    float4 w0 = *(const float4*)(W + (size_t)(k0 + bkk) * CB + col0 + bn);
    __syncthreads();  // previous iteration's LDS reads done
    As64[skb + 0][sm] = (double)x0.x; As64[skb + 1][sm] = (double)x0.y;
    As64[skb + 2][sm] = (double)x0.z; As64[skb + 3][sm] = (double)x0.w;
    As64[skb + 4][sm] = (double)x1.x; As64[skb + 5][sm] = (double)x1.y;
    As64[skb + 6][sm] = (double)x1.z; As64[skb + 7][sm] = (double)x1.w;
    Bs64[bkk][bn + 0] = (double)w0.x; Bs64[bkk][bn + 1] = (double)w0.y;
    Bs64[bkk][bn + 2] = (double)w0.z; Bs64[bkk][bn + 3] = (double)w0.w;
    __syncthreads();
#pragma unroll
    for (int kk = 0; kk < 16; ++kk) {
      const double* ar = &As64[kk][ty * 4];
      const double* br = &Bs64[kk][tx * 8];
      double a[4] = {ar[0], ar[1], ar[2], ar[3]};
      double b[8] = {br[0], br[1], br[2], br[3], br[4], br[5], br[6], br[7]};
#pragma unroll
      for (int i = 0; i < 4; ++i)
#pragma unroll
        for (int j = 0; j < 8; ++j)
          acc[i][j] += a[i] * b[j];
    }
  }

  double bb[8];
#pragma unroll
  for (int j = 0; j < 8; ++j) bb[j] = (double)bias[col0 + tx * 8 + j];
#pragma unroll
  for (int i = 0; i < 4; ++i) {
    int r = row0 + ty * 4 + i;
    int c0 = col0 + tx * 8;
    float vr[8];
    unsigned short vh[8], vl[8];
#pragma unroll
    for (int j = 0; j < 8; ++j) {
      float v = (float)(acc[i][j] + bb[j]);
      vr[j] = v;
      vh[j] = f2bf(v);
      vl[j] = f2bf(v - bf2f(vh[j]));
    }
    size_t o = (size_t)r * CB + c0;
    *(float4*)(R + o) = make_float4(vr[0], vr[1], vr[2], vr[3]);
    *(float4*)(R + o + 4) = make_float4(vr[4], vr[5], vr[6], vr[7]);
    size_t so = staged_off(r, c0);  // c0 aligned 8 -> j=0..7 contiguous
    *(ushort4*)(Rhi + so) = make_ushort4(vh[0], vh[1], vh[2], vh[3]);
    *(ushort4*)(Rhi + so + 4) = make_ushort4(vh[4], vh[5], vh[6], vh[7]);
    *(ushort4*)(Rlo + so) = make_ushort4(vl[0], vl[1], vl[2], vl[3]);
    *(ushort4*)(Rlo + so + 4) = make_ushort4(vl[4], vl[5], vl[6], vl[7]);
  }
}

// ---------------------------------------------------------------------------
// Stage 1: 3-term bf16-split MFMA distance GEMM, 128x128 tile, BK=32.
// Staged-layout inputs: every global_load_lds is 1KB contiguous.
// ---------------------------------------------------------------------------
__global__ __launch_bounds__(256) void vq_stage1(
    const unsigned short* __restrict__ Rhi, const unsigned short* __restrict__ Rlo,
    const unsigned short* __restrict__ Chi, const unsigned short* __restrict__ Clo,
    const float* __restrict__ cnormF, float4* __restrict__ cand) {
  __shared__ __align__(16) char lds[32768];  // Ahi,Alo,Bhi,Blo: 8KB each
  __shared__ float4 sRed[128][2];
  int tid = threadIdx.x;
  int wave = tid >> 6, lane = tid & 63;
  int wm = wave >> 1, wn = wave & 1;
  int q = lane >> 4, l15 = lane & 15;
  int g = blockIdx.x;
  int rb = (g & 7) + ((g >> 6) << 3);  // 8 col-blocks of rb share an XCD
  int cbk = (g >> 3) & 7;
  int row0 = rb * 128, n0 = cbk * 128;

  f32x4 acc[4][4];
#pragma unroll
  for (int i = 0; i < 4; ++i)
#pragma unroll
    for (int j = 0; j < 4; ++j)
      acc[i][j] = (f32x4){0.f, 0.f, 0.f, 0.f};

  // wave-uniform staging source (wave 0:Rhi 1:Rlo 2:Chi 3:Clo)
  const unsigned short* gsrc;
  int gbase;  // 16-row group index
  if (wave == 0)      { gsrc = Rhi; gbase = row0 >> 4; }
  else if (wave == 1) { gsrc = Rlo; gbase = row0 >> 4; }
  else if (wave == 2) { gsrc = Chi; gbase = n0 >> 4; }
  else                { gsrc = Clo; gbase = n0 >> 4; }
  const unsigned short* gw = gsrc + (size_t)gbase * 8192 + lane * 8;
  char* lbase = lds + wave * 8192;

  for (int kt = 0; kt < 16; ++kt) {
    __syncthreads();
#pragma unroll
    for (int s = 0; s < 8; ++s) {
      __builtin_amdgcn_global_load_lds(
          (const __attribute__((address_space(1))) void*)(gw + (size_t)s * 8192 + kt * 512),
          (__attribute__((address_space(3))) void*)(lbase + s * 1024), 16, 0, 0);
    }
    __syncthreads();

    short8 ahi[4], alo[4];
#pragma unroll
    for (int ti = 0; ti < 4; ++ti) {
      int pl = (wm * 4 + ti) * 1024 + lane * 16;
      ahi[ti] = *(const short8*)(lds + pl);
      alo[ti] = *(const short8*)(lds + 8192 + pl);
    }
#pragma unroll
    for (int tj = 0; tj < 4; ++tj) {
      int pl = (wn * 4 + tj) * 1024 + lane * 16;
      short8 bhi = *(const short8*)(lds + 16384 + pl);
      short8 blo = *(const short8*)(lds + 24576 + pl);
      // per-acc order stays hh,hl,lh per kt (bitwise identical to R6)
#pragma unroll
      for (int ti = 0; ti < 4; ++ti)
        acc[ti][tj] = __builtin_amdgcn_mfma_f32_16x16x32_bf16(ahi[ti], bhi, acc[ti][tj], 0, 0, 0);
#pragma unroll
      for (int ti = 0; ti < 4; ++ti)
        acc[ti][tj] = __builtin_amdgcn_mfma_f32_16x16x32_bf16(ahi[ti], blo, acc[ti][tj], 0, 0, 0);
#pragma unroll
      for (int ti = 0; ti < 4; ++ti)
        acc[ti][tj] = __builtin_amdgcn_mfma_f32_16x16x32_bf16(alo[ti], bhi, acc[ti][tj], 0, 0, 0);
    }
  }

  // Epilogue: d = cn - 2S; per-row top-2 over this wave's 64 cols, then
  // cross-wn merge via sRed.
  float cn[4]; int coln[4];
#pragma unroll
  for (int tj = 0; tj < 4; ++tj) {
    coln[tj] = n0 + wn * 64 + tj * 16 + l15;
    cn[tj] = cnormF[coln[tj]];
  }
#pragma unroll
  for (int ti = 0; ti < 4; ++ti) {
#pragma unroll
    for (int r = 0; r < 4; ++r) {
      float m1 = FLT_MAX, m2 = FLT_MAX;
      int i1 = INT_MAX, i2 = INT_MAX;
#pragma unroll
      for (int tj = 0; tj < 4; ++tj) {
        float v = cn[tj] - 2.0f * acc[ti][tj][r];
        int ix = coln[tj];
        if (v < m1 || (v == m1 && ix < i1)) {
          m2 = m1; i2 = i1; m1 = v; i1 = ix;
        } else if (v < m2 || (v == m2 && ix < i2)) {
          m2 = v; i2 = ix;
        }
      }
#pragma unroll
      for (int mask = 1; mask <= 8; mask <<= 1) {
        float om1 = __shfl_xor(m1, mask, 64);
        int   oi1 = __shfl_xor(i1, mask, 64);
        float om2 = __shfl_xor(m2, mask, 64);
        int   oi2 = __shfl_xor(i2, mask, 64);
        if (om1 < m1 || (om1 == m1 && oi1 < i1)) {
          m2 = m1; i2 = i1; m1 = om1; i1 = oi1;
        } else if (om1 < m2 || (om1 == m2 && oi1 < i2)) {
          m2 = om1; i2 = oi1;
        }
        if (om2 < m1 || (om2 == m1 && oi2 < i1)) {
          m2 = m1; i2 = i1; m1 = om2; i1 = oi2;
        } else if (om2 < m2 || (om2 == m2 && oi2 < i2)) {
          m2 = om2; i2 = oi2;
        }
      }
      if (l15 == 0) {
        int rit = wm * 64 + ti * 16 + q * 4 + r;
        sRed[rit][wn] =
            make_float4(m1, __int_as_float(i1), m2, __int_as_float(i2));
      }
    }
  }
  __syncthreads();

  if (tid < 128) {
    float4 e0 = sRed[tid][0], e1 = sRed[tid][1];
    float v[4] = {e0.x, e0.z, e1.x, e1.z};
    int ix[4] = {__float_as_int(e0.y), __float_as_int(e0.w),
                 __float_as_int(e1.y), __float_as_int(e1.w)};
    float M1 = FLT_MAX, M2 = FLT_MAX;
    int I1 = INT_MAX, I2 = INT_MAX;
#pragma unroll
    for (int p = 0; p < 4; ++p) {
      if (v[p] < M1 || (v[p] == M1 && ix[p] < I1)) {
        M2 = M1; I2 = I1; M1 = v[p]; I1 = ix[p];
      } else if (v[p] < M2 || (v[p] == M2 && ix[p] < I2)) {
        M2 = v[p]; I2 = ix[p];
      }
    }
    cand[(size_t)(row0 + tid) * 8 + cbk] =
        make_float4(M1, __int_as_float(I1), M2, __int_as_float(I2));
  }
}

// ---------------------------------------------------------------------------
// Stage 2: combine 8 chunk top-2s; fp64-refine near-ties (vs fp32 R);
// write id; update residual (row-major R) + staged-layout Rhi/Rlo.
// ---------------------------------------------------------------------------
__global__ __launch_bounds__(256) void vq_refine(
    const float* __restrict__ cb, const double* __restrict__ cnorm,
    const float4* __restrict__ cand, float* __restrict__ R,
    unsigned short* __restrict__ Rhi, unsigned short* __restrict__ Rlo,
    float* __restrict__ idsF, int layer) {
  __shared__ int sIdx[64][16];
  __shared__ int sCnt[64];
  __shared__ int sBest[64];

  int tid = threadIdx.x;
  int row0 = blockIdx.x * 64;

  if (tid < 64) {
    int row = row0 + tid;
    float v[16]; int ix[16];
#pragma unroll
    for (int c = 0; c < 8; ++c) {
      float4 e = cand[(size_t)row * 8 + c];
      v[2 * c] = e.x;     ix[2 * c] = __float_as_int(e.y);
      v[2 * c + 1] = e.z; ix[2 * c + 1] = __float_as_int(e.w);
    }
    float M = FLT_MAX; int I = INT_MAX;
#pragma unroll
    for (int p = 0; p < 16; ++p)
      if (v[p] < M || (v[p] == M && ix[p] < I)) { M = v[p]; I = ix[p]; }
    int cnt = 0;
#pragma unroll
    for (int p = 0; p < 16; ++p)
      if (v[p] < M + DELTA && cnt < 16) sIdx[tid][cnt++] = ix[p];
    sCnt[tid] = cnt;
    sBest[tid] = I;
  }
  __syncthreads();

  int wave = tid >> 6, lane = tid & 63;
  for (int r = wave * 16; r < wave * 16 + 16; ++r) {
    int cnt = sCnt[r];
    if (cnt < 2) continue;
    double bestD = 1e300; int bestI = INT_MAX;
    const float* rrow = R + (size_t)(row0 + r) * CB;
    for (int c = 0; c < cnt; ++c) {
      int idx = sIdx[r][c];
      const float* crow = cb + (size_t)idx * CB;
      double s = 0.0;
      for (int e = lane; e < CB; e += 64)
        s += (double)rrow[e] * (double)crow[e];
#pragma unroll
      for (int off = 32; off > 0; off >>= 1)
        s += __shfl_xor(s, off, 64);
      double d = cnorm[idx] - 2.0 * s;
      if (d < bestD || (d == bestD && idx < bestI)) { bestD = d; bestI = idx; }
    }
    if (lane == 0) sBest[r] = bestI;
  }
  __syncthreads();

  if (tid < 64)
    idsF[(size_t)(row0 + tid) * NL + layer] = (float)sBest[tid];

  // residual update: 4 elements per thread per iter
  for (int it = tid; it < 64 * (CB / 4); it += 256) {
    int r = it >> 7, dq = (it & 127) * 4;
    int row = row0 + r;
    size_t o = (size_t)row * CB + dq;
    float4 rv = *(const float4*)(R + o);
    const float* crow = cb + (size_t)sBest[r] * CB + dq;
    float nv[4] = {rv.x - crow[0], rv.y - crow[1], rv.z - crow[2], rv.w - crow[3]};
    *(float4*)(R + o) = make_float4(nv[0], nv[1], nv[2], nv[3]);
    unsigned short vh[4], vl[4];
#pragma unroll
    for (int j = 0; j < 4; ++j) {
      vh[j] = f2bf(nv[j]);
      vl[j] = f2bf(nv[j] - bf2f(vh[j]));
    }
    size_t so = staged_off(row, dq);  // dq aligned 4 -> one chunk
    *(ushort4*)(Rhi + so) = make_ushort4(vh[0], vh[1], vh[2], vh[3]);
    *(ushort4*)(Rlo + so) = make_ushort4(vl[0], vl[1], vl[2], vl[3]);
  }
}

// ---------------------------------------------------------------------------
// recon[b][j] = dec_b[j] + sum_l ids[b][l] * dec_W[l][j]
// ---------------------------------------------------------------------------
__global__ __launch_bounds__(256) void recon_kernel(
    const float* __restrict__ idsF, const float* __restrict__ decW,
    const float* __restrict__ decb, float* __restrict__ recon) {
  int g = blockIdx.x * 256 + threadIdx.x;
  int b = g >> 9, j = g & (CB - 1);
  float s = decb[j];
#pragma unroll
  for (int l = 0; l < NL; ++l)
    s += idsF[(size_t)b * NL + l] * decW[l * CB + j];
  recon[g] = s;
}

extern "C" void kernel_launch(void* const* d_in, const int* in_sizes, int n_in,
                              void* d_out, int out_size, void* d_ws, size_t ws_size,
                              hipStream_t stream) {
  const float* X    = (const float*)d_in[0];
  const float* encW = (const float*)d_in[1];
  const float* encb = (const float*)d_in[2];
  const float* cbs  = (const float*)d_in[3];
  const float* decW = (const float*)d_in[4];
  const float* decb = (const float*)d_in[5];

  float* out = (float*)d_out;
  float* recon = out;
  float* idsF = out + (size_t)BB * CB;

  char* ws = (char*)d_ws;
  float* R = (float*)ws;                 ws += (size_t)BB * CB * 4;        // 32 MB
  unsigned short* Rhi = (unsigned short*)ws; ws += (size_t)BB * CB * 2;    // 16 MB
  unsigned short* Rlo = (unsigned short*)ws; ws += (size_t)BB * CB * 2;    // 16 MB
  unsigned short* Chi = (unsigned short*)ws; ws += (size_t)NL * KC * CB * 2; // 4 MB
  unsigned short* Clo = (unsigned short*)ws; ws += (size_t)NL * KC * CB * 2; // 4 MB
  double* cnorm = (double*)ws;           ws += (size_t)NL * KC * 8;        // 32 KB
  float* cnormF = (float*)ws;            ws += (size_t)NL * KC * 4;        // 16 KB
  float4* cand = (float4*)ws;            // [BB][8] float4 = 2 MB

  cbsplit_kernel<<<(NL * KC * CB) / 1024, 256, 0, stream>>>(cbs, Chi, Clo);
  cnorm_kernel<<<(NL * KC) / 4, 256, 0, stream>>>(cbs, cnorm, cnormF);
  enc_gemm<<<(BB / 128) * (CB / 64), 256, 0, stream>>>(X, encW, encb, R, Rhi, Rlo);
  for (int l = 0; l < NL; ++l) {
    const float* cbl = cbs + (size_t)l * KC * CB;
    vq_stage1<<<(BB / 128) * 8, 256, 0, stream>>>(
        Rhi, Rlo, Chi + (size_t)l * KC * CB, Clo + (size_t)l * KC * CB,
        cnormF + (size_t)l * KC, cand);
    vq_refine<<<BB / 64, 256, 0, stream>>>(cbl, cnorm + (size_t)l * KC, cand,
                                           R, Rhi, Rlo, idsF, l);
  }
  recon_kernel<<<(BB * CB) / 256, 256, 0, stream>>>(idsF, decW, decb, recon);
}

// Round 9
// 837.824 us; speedup vs baseline: 1.1307x; 1.1307x over previous
//
#include <hip/hip_runtime.h>
#include <float.h>
#include <limits.h>

// Problem constants
#define BB 16384   // batch rows
#define DIN 1024   // encoder input dim
#define CB 512     // codebook dim
#define KC 1024    // codewords per layer
#define NL 4       // layers

// Refine margin: must exceed stage1 bf16-split noise (~1e-3). ~10x slack.
#define DELTA 0.01f

typedef __attribute__((ext_vector_type(8))) short short8;
typedef __attribute__((ext_vector_type(4))) float f32x4;
typedef __attribute__((ext_vector_type(4))) double f64x4;

__device__ __forceinline__ unsigned short f2bf(float f) {
  unsigned int u = __float_as_uint(f);
  u = u + 0x7fffu + ((u >> 16) & 1u);
  return (unsigned short)(u >> 16);
}
__device__ __forceinline__ float bf2f(unsigned short h) {
  return __uint_as_float(((unsigned int)h) << 16);
}

// Staged layout (shorts) for matrix M[rows][512]:
//   off(row,k) = ((row>>4)*16 + (k>>5))*512 + (((k>>3)&3)*16 + (row&15))*8 + (k&7)
// = MFMA A/B fragment lane image; staging = contiguous 1KB loads.
__device__ __forceinline__ size_t staged_off(int row, int k) {
  return ((size_t)(row >> 4) * 16 + (k >> 5)) * 512 +
         (((k >> 3) & 3) * 16 + (row & 15)) * 8 + (k & 7);
}

// ---------------------------------------------------------------------------
// Split codebooks into bf16 hi/lo, written in staged layout.
// ---------------------------------------------------------------------------
__global__ __launch_bounds__(256) void cbsplit_kernel(
    const float* __restrict__ cbs, unsigned short* __restrict__ Chi,
    unsigned short* __restrict__ Clo) {
  int g = (blockIdx.x * 256 + threadIdx.x) * 4;  // flat over NL*KC*CB
  int k = g & (CB - 1);
  int lr = g >> 9;
  int layer = lr >> 10, row = lr & (KC - 1);
  float4 v = *(const float4*)(cbs + g);
  float vv[4] = {v.x, v.y, v.z, v.w};
  unsigned short hh[4], ll[4];
#pragma unroll
  for (int i = 0; i < 4; ++i) {
    hh[i] = f2bf(vv[i]);
    ll[i] = f2bf(vv[i] - bf2f(hh[i]));
  }
  size_t off = (size_t)layer * (KC / 16) * 8192 + staged_off(row, k);
  *(ushort4*)(Chi + off) = make_ushort4(hh[0], hh[1], hh[2], hh[3]);
  *(ushort4*)(Clo + off) = make_ushort4(ll[0], ll[1], ll[2], ll[3]);
}

// ---------------------------------------------------------------------------
// Split residual R into staged bf16 hi/lo (after enc_gemm).
// ---------------------------------------------------------------------------
__global__ __launch_bounds__(256) void rsplit_kernel(
    const float* __restrict__ R, unsigned short* __restrict__ Rhi,
    unsigned short* __restrict__ Rlo) {
  int g = (blockIdx.x * 256 + threadIdx.x) * 4;
  int k = g & (CB - 1);
  int row = g >> 9;
  float4 v = *(const float4*)(R + g);
  float vv[4] = {v.x, v.y, v.z, v.w};
  unsigned short hh[4], ll[4];
#pragma unroll
  for (int i = 0; i < 4; ++i) {
    hh[i] = f2bf(vv[i]);
    ll[i] = f2bf(vv[i] - bf2f(hh[i]));
  }
  size_t off = staged_off(row, k);
  *(ushort4*)(Rhi + off) = make_ushort4(hh[0], hh[1], hh[2], hh[3]);
  *(ushort4*)(Rlo + off) = make_ushort4(ll[0], ll[1], ll[2], ll[3]);
}

// ---------------------------------------------------------------------------
// cnorm[l*KC+k] = ||codebooks[l][k]||^2, fp64 (refine) + fp32 (stage1)
// ---------------------------------------------------------------------------
__global__ __launch_bounds__(256) void cnorm_kernel(
    const float* __restrict__ cbs, double* __restrict__ cnorm,
    float* __restrict__ cnormF) {
  int gw = (blockIdx.x * blockDim.x + threadIdx.x) >> 6;
  int lane = threadIdx.x & 63;
  if (gw >= NL * KC) return;
  const float* row = cbs + (size_t)gw * CB;
  double s = 0.0;
  for (int i = lane; i < CB; i += 64) {
    double v = (double)row[i];
    s += v * v;
  }
#pragma unroll
  for (int off = 32; off > 0; off >>= 1)
    s += __shfl_down(s, off, 64);
  if (lane == 0) { cnorm[gw] = s; cnormF[gw] = (float)s; }
}

// ---------------------------------------------------------------------------
// Encoder GEMM via v_mfma_f64_16x16x4 (matrix pipe, spec 78.6 TF).
// 128x64 block, 4 waves x 32 rows x 64 cols. C/D register layout is
// determined AT RUNTIME by two probe MFMAs (accP -> row idx, accQ -> col
// idx per (lane,reg)); the probe measures the composite of my operand
// placement and the HW layout, so the epilogue is correct for any C/D
// mapping and any row/col operand permutation (only assumes A and B share
// the same lane->k extraction).
// fp64 accumulation, k-ascending -> same decisions as the verified vector
// path downstream.
// ---------------------------------------------------------------------------
__global__ __launch_bounds__(256, 4) void enc_gemm(
    const float* __restrict__ X, const float* __restrict__ W,
    const float* __restrict__ bias, float* __restrict__ R) {
  __shared__ double As[128][18];  // [m][kk], pad 18
  __shared__ double Bs[16][66];   // [kk][n], pad 66
  int tid = threadIdx.x;
  int wave = tid >> 6, lane = tid & 63;
  int q = lane >> 4, l15 = lane & 15;
  int g = blockIdx.x;
  int rb = (g & 7) + ((g >> 6) << 3);  // 8 col-blocks of rb share an XCD
  int cb8 = (g >> 3) & 7;
  int row0 = rb * 128, col0 = cb8 * 64;

  // --- layout probes ---
  f64x4 accP = (f64x4){0.0, 0.0, 0.0, 0.0};
  f64x4 accQ = (f64x4){0.0, 0.0, 0.0, 0.0};
  {
    double sel = (q == 0) ? 1.0 : 0.0;
    accP = __builtin_amdgcn_mfma_f64_16x16x4f64((double)l15, sel, accP, 0, 0, 0);
    accQ = __builtin_amdgcn_mfma_f64_16x16x4f64(sel, (double)l15, accQ, 0, 0, 0);
  }
  int rI[4], cI[4];
#pragma unroll
  for (int r = 0; r < 4; ++r) { rI[r] = (int)accP[r]; cI[r] = (int)accQ[r]; }

  int sm = tid >> 1, skb = (tid & 1) * 8;   // A staging: row, k-base
  int bkk = tid >> 4, bn = (tid & 15) * 4;  // B staging: kk, col

  f64x4 acc[2][4];
#pragma unroll
  for (int i = 0; i < 2; ++i)
#pragma unroll
    for (int j = 0; j < 4; ++j)
      acc[i][j] = (f64x4){0.0, 0.0, 0.0, 0.0};

  for (int k0 = 0; k0 < DIN; k0 += 16) {
    float4 x0 = *(const float4*)(X + (size_t)(row0 + sm) * DIN + k0 + skb);
    float4 x1 = *(const float4*)(X + (size_t)(row0 + sm) * DIN + k0 + skb + 4);
    float4 w0 = *(const float4*)(W + (size_t)(k0 + bkk) * CB + col0 + bn);
    __syncthreads();  // previous iteration's LDS reads done
    As[sm][skb + 0] = (double)x0.x; As[sm][skb + 1] = (double)x0.y;
    As[sm][skb + 2] = (double)x0.z; As[sm][skb + 3] = (double)x0.w;
    As[sm][skb + 4] = (double)x1.x; As[sm][skb + 5] = (double)x1.y;
    As[sm][skb + 6] = (double)x1.z; As[sm][skb + 7] = (double)x1.w;
    Bs[bkk][bn + 0] = (double)w0.x; Bs[bkk][bn + 1] = (double)w0.y;
    Bs[bkk][bn + 2] = (double)w0.z; Bs[bkk][bn + 3] = (double)w0.w;
    __syncthreads();
#pragma unroll
    for (int s = 0; s < 4; ++s) {
      int kk = s * 4 + q;
      double a0 = As[wave * 32 + l15][kk];
      double a1 = As[wave * 32 + 16 + l15][kk];
      double b0 = Bs[kk][l15];
      double b1 = Bs[kk][16 + l15];
      double b2 = Bs[kk][32 + l15];
      double b3 = Bs[kk][48 + l15];
      acc[0][0] = __builtin_amdgcn_mfma_f64_16x16x4f64(a0, b0, acc[0][0], 0, 0, 0);
      acc[0][1] = __builtin_amdgcn_mfma_f64_16x16x4f64(a0, b1, acc[0][1], 0, 0, 0);
      acc[0][2] = __builtin_amdgcn_mfma_f64_16x16x4f64(a0, b2, acc[0][2], 0, 0, 0);
      acc[0][3] = __builtin_amdgcn_mfma_f64_16x16x4f64(a0, b3, acc[0][3], 0, 0, 0);
      acc[1][0] = __builtin_amdgcn_mfma_f64_16x16x4f64(a1, b0, acc[1][0], 0, 0, 0);
      acc[1][1] = __builtin_amdgcn_mfma_f64_16x16x4f64(a1, b1, acc[1][1], 0, 0, 0);
      acc[1][2] = __builtin_amdgcn_mfma_f64_16x16x4f64(a1, b2, acc[1][2], 0, 0, 0);
      acc[1][3] = __builtin_amdgcn_mfma_f64_16x16x4f64(a1, b3, acc[1][3], 0, 0, 0);
    }
  }

  // Epilogue: scatter via probed (row, col) mapping. Scalar stores.
#pragma unroll
  for (int ti = 0; ti < 2; ++ti) {
#pragma unroll
    for (int tj = 0; tj < 4; ++tj) {
#pragma unroll
      for (int r = 0; r < 4; ++r) {
        int row = row0 + wave * 32 + ti * 16 + rI[r];
        int col = col0 + tj * 16 + cI[r];
        R[(size_t)row * CB + col] =
            (float)(acc[ti][tj][r] + (double)bias[col]);
      }
    }
  }
}

// ---------------------------------------------------------------------------
// Stage 1: 3-term bf16-split MFMA distance GEMM, 128x128 tile, BK=32.
// Staged-layout inputs: every global_load_lds is 1KB contiguous.
// ---------------------------------------------------------------------------
__global__ __launch_bounds__(256) void vq_stage1(
    const unsigned short* __restrict__ Rhi, const unsigned short* __restrict__ Rlo,
    const unsigned short* __restrict__ Chi, const unsigned short* __restrict__ Clo,
    const float* __restrict__ cnormF, float4* __restrict__ cand) {
  __shared__ __align__(16) char lds[32768];  // Ahi,Alo,Bhi,Blo: 8KB each
  __shared__ float4 sRed[128][2];
  int tid = threadIdx.x;
  int wave = tid >> 6, lane = tid & 63;
  int wm = wave >> 1, wn = wave & 1;
  int q = lane >> 4, l15 = lane & 15;
  int g = blockIdx.x;
  int rb = (g & 7) + ((g >> 6) << 3);  // 8 col-blocks of rb share an XCD
  int cbk = (g >> 3) & 7;
  int row0 = rb * 128, n0 = cbk * 128;

  f32x4 acc[4][4];
#pragma unroll
  for (int i = 0; i < 4; ++i)
#pragma unroll
    for (int j = 0; j < 4; ++j)
      acc[i][j] = (f32x4){0.f, 0.f, 0.f, 0.f};

  // wave-uniform staging source (wave 0:Rhi 1:Rlo 2:Chi 3:Clo)
  const unsigned short* gsrc;
  int gbase;  // 16-row group index
  if (wave == 0)      { gsrc = Rhi; gbase = row0 >> 4; }
  else if (wave == 1) { gsrc = Rlo; gbase = row0 >> 4; }
  else if (wave == 2) { gsrc = Chi; gbase = n0 >> 4; }
  else                { gsrc = Clo; gbase = n0 >> 4; }
  const unsigned short* gw = gsrc + (size_t)gbase * 8192 + lane * 8;
  char* lbase = lds + wave * 8192;

  for (int kt = 0; kt < 16; ++kt) {
    __syncthreads();
#pragma unroll
    for (int s = 0; s < 8; ++s) {
      __builtin_amdgcn_global_load_lds(
          (const __attribute__((address_space(1))) void*)(gw + (size_t)s * 8192 + kt * 512),
          (__attribute__((address_space(3))) void*)(lbase + s * 1024), 16, 0, 0);
    }
    __syncthreads();

    short8 ahi[4], alo[4];
#pragma unroll
    for (int ti = 0; ti < 4; ++ti) {
      int pl = (wm * 4 + ti) * 1024 + lane * 16;
      ahi[ti] = *(const short8*)(lds + pl);
      alo[ti] = *(const short8*)(lds + 8192 + pl);
    }
#pragma unroll
    for (int tj = 0; tj < 4; ++tj) {
      int pl = (wn * 4 + tj) * 1024 + lane * 16;
      short8 bhi = *(const short8*)(lds + 16384 + pl);
      short8 blo = *(const short8*)(lds + 24576 + pl);
      // per-acc order stays hh,hl,lh per kt (bitwise identical to R6)
#pragma unroll
      for (int ti = 0; ti < 4; ++ti)
        acc[ti][tj] = __builtin_amdgcn_mfma_f32_16x16x32_bf16(ahi[ti], bhi, acc[ti][tj], 0, 0, 0);
#pragma unroll
      for (int ti = 0; ti < 4; ++ti)
        acc[ti][tj] = __builtin_amdgcn_mfma_f32_16x16x32_bf16(ahi[ti], blo, acc[ti][tj], 0, 0, 0);
#pragma unroll
      for (int ti = 0; ti < 4; ++ti)
        acc[ti][tj] = __builtin_amdgcn_mfma_f32_16x16x32_bf16(alo[ti], bhi, acc[ti][tj], 0, 0, 0);
    }
  }

  // Epilogue: d = cn - 2S; per-row top-2 over this wave's 64 cols, then
  // cross-wn merge via sRed.
  float cn[4]; int coln[4];
#pragma unroll
  for (int tj = 0; tj < 4; ++tj) {
    coln[tj] = n0 + wn * 64 + tj * 16 + l15;
    cn[tj] = cnormF[coln[tj]];
  }
#pragma unroll
  for (int ti = 0; ti < 4; ++ti) {
#pragma unroll
    for (int r = 0; r < 4; ++r) {
      float m1 = FLT_MAX, m2 = FLT_MAX;
      int i1 = INT_MAX, i2 = INT_MAX;
#pragma unroll
      for (int tj = 0; tj < 4; ++tj) {
        float v = cn[tj] - 2.0f * acc[ti][tj][r];
        int ix = coln[tj];
        if (v < m1 || (v == m1 && ix < i1)) {
          m2 = m1; i2 = i1; m1 = v; i1 = ix;
        } else if (v < m2 || (v == m2 && ix < i2)) {
          m2 = v; i2 = ix;
        }
      }
#pragma unroll
      for (int mask = 1; mask <= 8; mask <<= 1) {
        float om1 = __shfl_xor(m1, mask, 64);
        int   oi1 = __shfl_xor(i1, mask, 64);
        float om2 = __shfl_xor(m2, mask, 64);
        int   oi2 = __shfl_xor(i2, mask, 64);
        if (om1 < m1 || (om1 == m1 && oi1 < i1)) {
          m2 = m1; i2 = i1; m1 = om1; i1 = oi1;
        } else if (om1 < m2 || (om1 == m2 && oi1 < i2)) {
          m2 = om1; i2 = oi1;
        }
        if (om2 < m1 || (om2 == m1 && oi2 < i1)) {
          m2 = m1; i2 = i1; m1 = om2; i1 = oi2;
        } else if (om2 < m2 || (om2 == m2 && oi2 < i2)) {
          m2 = om2; i2 = oi2;
        }
      }
      if (l15 == 0) {
        int rit = wm * 64 + ti * 16 + q * 4 + r;
        sRed[rit][wn] =
            make_float4(m1, __int_as_float(i1), m2, __int_as_float(i2));
      }
    }
  }
  __syncthreads();

  if (tid < 128) {
    float4 e0 = sRed[tid][0], e1 = sRed[tid][1];
    float v[4] = {e0.x, e0.z, e1.x, e1.z};
    int ix[4] = {__float_as_int(e0.y), __float_as_int(e0.w),
                 __float_as_int(e1.y), __float_as_int(e1.w)};
    float M1 = FLT_MAX, M2 = FLT_MAX;
    int I1 = INT_MAX, I2 = INT_MAX;
#pragma unroll
    for (int p = 0; p < 4; ++p) {
      if (v[p] < M1 || (v[p] == M1 && ix[p] < I1)) {
        M2 = M1; I2 = I1; M1 = v[p]; I1 = ix[p];
      } else if (v[p] < M2 || (v[p] == M2 && ix[p] < I2)) {
        M2 = v[p]; I2 = ix[p];
      }
    }
    cand[(size_t)(row0 + tid) * 8 + cbk] =
        make_float4(M1, __int_as_float(I1), M2, __int_as_float(I2));
  }
}

// ---------------------------------------------------------------------------
// Stage 2: combine 8 chunk top-2s; fp64-refine near-ties (vs fp32 R);
// write id; update residual (row-major R) + staged-layout Rhi/Rlo.
// ---------------------------------------------------------------------------
__global__ __launch_bounds__(256) void vq_refine(
    const float* __restrict__ cb, const double* __restrict__ cnorm,
    const float4* __restrict__ cand, float* __restrict__ R,
    unsigned short* __restrict__ Rhi, unsigned short* __restrict__ Rlo,
    float* __restrict__ idsF, int layer) {
  __shared__ int sIdx[64][16];
  __shared__ int sCnt[64];
  __shared__ int sBest[64];

  int tid = threadIdx.x;
  int row0 = blockIdx.x * 64;

  if (tid < 64) {
    int row = row0 + tid;
    float v[16]; int ix[16];
#pragma unroll
    for (int c = 0; c < 8; ++c) {
      float4 e = cand[(size_t)row * 8 + c];
      v[2 * c] = e.x;     ix[2 * c] = __float_as_int(e.y);
      v[2 * c + 1] = e.z; ix[2 * c + 1] = __float_as_int(e.w);
    }
    float M = FLT_MAX; int I = INT_MAX;
#pragma unroll
    for (int p = 0; p < 16; ++p)
      if (v[p] < M || (v[p] == M && ix[p] < I)) { M = v[p]; I = ix[p]; }
    int cnt = 0;
#pragma unroll
    for (int p = 0; p < 16; ++p)
      if (v[p] < M + DELTA && cnt < 16) sIdx[tid][cnt++] = ix[p];
    sCnt[tid] = cnt;
    sBest[tid] = I;
  }
  __syncthreads();

  int wave = tid >> 6, lane = tid & 63;
  for (int r = wave * 16; r < wave * 16 + 16; ++r) {
    int cnt = sCnt[r];
    if (cnt < 2) continue;
    double bestD = 1e300; int bestI = INT_MAX;
    const float* rrow = R + (size_t)(row0 + r) * CB;
    for (int c = 0; c < cnt; ++c) {
      int idx = sIdx[r][c];
      const float* crow = cb + (size_t)idx * CB;
      double s = 0.0;
      for (int e = lane; e < CB; e += 64)
        s += (double)rrow[e] * (double)crow[e];
#pragma unroll
      for (int off = 32; off > 0; off >>= 1)
        s += __shfl_xor(s, off, 64);
      double d = cnorm[idx] - 2.0 * s;
      if (d < bestD || (d == bestD && idx < bestI)) { bestD = d; bestI = idx; }
    }
    if (lane == 0) sBest[r] = bestI;
  }
  __syncthreads();

  if (tid < 64)
    idsF[(size_t)(row0 + tid) * NL + layer] = (float)sBest[tid];

  // residual update: 4 elements per thread per iter
  for (int it = tid; it < 64 * (CB / 4); it += 256) {
    int r = it >> 7, dq = (it & 127) * 4;
    int row = row0 + r;
    size_t o = (size_t)row * CB + dq;
    float4 rv = *(const float4*)(R + o);
    const float* crow = cb + (size_t)sBest[r] * CB + dq;
    float nv[4] = {rv.x - crow[0], rv.y - crow[1], rv.z - crow[2], rv.w - crow[3]};
    *(float4*)(R + o) = make_float4(nv[0], nv[1], nv[2], nv[3]);
    unsigned short vh[4], vl[4];
#pragma unroll
    for (int j = 0; j < 4; ++j) {
      vh[j] = f2bf(nv[j]);
      vl[j] = f2bf(nv[j] - bf2f(vh[j]));
    }
    size_t so = staged_off(row, dq);  // dq aligned 4 -> one chunk
    *(ushort4*)(Rhi + so) = make_ushort4(vh[0], vh[1], vh[2], vh[3]);
    *(ushort4*)(Rlo + so) = make_ushort4(vl[0], vl[1], vl[2], vl[3]);
  }
}

// ---------------------------------------------------------------------------
// recon[b][j] = dec_b[j] + sum_l ids[b][l] * dec_W[l][j]
// ---------------------------------------------------------------------------
__global__ __launch_bounds__(256) void recon_kernel(
    const float* __restrict__ idsF, const float* __restrict__ decW,
    const float* __restrict__ decb, float* __restrict__ recon) {
  int g = blockIdx.x * 256 + threadIdx.x;
  int b = g >> 9, j = g & (CB - 1);
  float s = decb[j];
#pragma unroll
  for (int l = 0; l < NL; ++l)
    s += idsF[(size_t)b * NL + l] * decW[l * CB + j];
  recon[g] = s;
}

extern "C" void kernel_launch(void* const* d_in, const int* in_sizes, int n_in,
                              void* d_out, int out_size, void* d_ws, size_t ws_size,
                              hipStream_t stream) {
  const float* X    = (const float*)d_in[0];
  const float* encW = (const float*)d_in[1];
  const float* encb = (const float*)d_in[2];
  const float* cbs  = (const float*)d_in[3];
  const float* decW = (const float*)d_in[4];
  const float* decb = (const float*)d_in[5];

  float* out = (float*)d_out;
  float* recon = out;
  float* idsF = out + (size_t)BB * CB;

  char* ws = (char*)d_ws;
  float* R = (float*)ws;                 ws += (size_t)BB * CB * 4;        // 32 MB
  unsigned short* Rhi = (unsigned short*)ws; ws += (size_t)BB * CB * 2;    // 16 MB
  unsigned short* Rlo = (unsigned short*)ws; ws += (size_t)BB * CB * 2;    // 16 MB
  unsigned short* Chi = (unsigned short*)ws; ws += (size_t)NL * KC * CB * 2; // 4 MB
  unsigned short* Clo = (unsigned short*)ws; ws += (size_t)NL * KC * CB * 2; // 4 MB
  double* cnorm = (double*)ws;           ws += (size_t)NL * KC * 8;        // 32 KB
  float* cnormF = (float*)ws;            ws += (size_t)NL * KC * 4;        // 16 KB
  float4* cand = (float4*)ws;            // [BB][8] float4 = 2 MB

  cbsplit_kernel<<<(NL * KC * CB) / 1024, 256, 0, stream>>>(cbs, Chi, Clo);
  cnorm_kernel<<<(NL * KC) / 4, 256, 0, stream>>>(cbs, cnorm, cnormF);
  enc_gemm<<<(BB / 128) * (CB / 64), 256, 0, stream>>>(X, encW, encb, R);
  rsplit_kernel<<<(BB * CB) / 1024, 256, 0, stream>>>(R, Rhi, Rlo);
  for (int l = 0; l < NL; ++l) {
    const float* cbl = cbs + (size_t)l * KC * CB;
    vq_stage1<<<(BB / 128) * 8, 256, 0, stream>>>(
        Rhi, Rlo, Chi + (size_t)l * KC * CB, Clo + (size_t)l * KC * CB,
        cnormF + (size_t)l * KC, cand);
    vq_refine<<<BB / 64, 256, 0, stream>>>(cbl, cnorm + (size_t)l * KC, cand,
                                           R, Rhi, Rlo, idsF, l);
  }
  recon_kernel<<<(BB * CB) / 256, 256, 0, stream>>>(idsF, decW, decb, recon);
}

// Round 10
// 744.240 us; speedup vs baseline: 1.2729x; 1.1257x over previous
//
#include <hip/hip_runtime.h>
#include <float.h>
#include <limits.h>

// Problem constants
#define BB 16384   // batch rows
#define DIN 1024   // encoder input dim
#define CB 512     // codebook dim
#define KC 1024    // codewords per layer
#define NL 4       // layers

// Refine margin: fp16 1-term distance noise std ~0.022, max ~0.13.
// 0.25 = ~8 sigma AND >= 2x max single-value error (certainty bound).
#define DELTA 0.25f

typedef __attribute__((ext_vector_type(8))) _Float16 half8;
typedef __attribute__((ext_vector_type(4))) float f32x4;
typedef __attribute__((ext_vector_type(4))) double f64x4;

__device__ __forceinline__ unsigned short f2h(float f) {
  _Float16 h = (_Float16)f;  // RTN
  return *(unsigned short*)&h;
}

// Staged layout (shorts) for matrix M[rows][512]:
//   off(row,k) = ((row>>4)*16 + (k>>5))*512 + (((k>>3)&3)*16 + (row&15))*8 + (k&7)
// = MFMA A/B fragment lane image; staging = contiguous 1KB loads.
__device__ __forceinline__ size_t staged_off(int row, int k) {
  return ((size_t)(row >> 4) * 16 + (k >> 5)) * 512 +
         (((k >> 3) & 3) * 16 + (row & 15)) * 8 + (k & 7);
}

// ---------------------------------------------------------------------------
// Codebooks -> fp16, staged layout.
// ---------------------------------------------------------------------------
__global__ __launch_bounds__(256) void cbsplit_kernel(
    const float* __restrict__ cbs, unsigned short* __restrict__ Ch16) {
  int g = (blockIdx.x * 256 + threadIdx.x) * 4;  // flat over NL*KC*CB
  int k = g & (CB - 1);
  int lr = g >> 9;
  int layer = lr >> 10, row = lr & (KC - 1);
  float4 v = *(const float4*)(cbs + g);
  size_t off = (size_t)layer * (KC / 16) * 8192 + staged_off(row, k);
  *(ushort4*)(Ch16 + off) = make_ushort4(f2h(v.x), f2h(v.y), f2h(v.z), f2h(v.w));
}

// ---------------------------------------------------------------------------
// Residual -> fp16, staged layout (after enc_gemm).
// ---------------------------------------------------------------------------
__global__ __launch_bounds__(256) void rsplit_kernel(
    const float* __restrict__ R, unsigned short* __restrict__ Rh16) {
  int g = (blockIdx.x * 256 + threadIdx.x) * 4;
  int k = g & (CB - 1);
  int row = g >> 9;
  float4 v = *(const float4*)(R + g);
  size_t off = staged_off(row, k);
  *(ushort4*)(Rh16 + off) = make_ushort4(f2h(v.x), f2h(v.y), f2h(v.z), f2h(v.w));
}

// ---------------------------------------------------------------------------
// cnorm[l*KC+k] = ||codebooks[l][k]||^2, fp64 (refine) + fp32 (stage1)
// ---------------------------------------------------------------------------
__global__ __launch_bounds__(256) void cnorm_kernel(
    const float* __restrict__ cbs, double* __restrict__ cnorm,
    float* __restrict__ cnormF) {
  int gw = (blockIdx.x * blockDim.x + threadIdx.x) >> 6;
  int lane = threadIdx.x & 63;
  if (gw >= NL * KC) return;
  const float* row = cbs + (size_t)gw * CB;
  double s = 0.0;
  for (int i = lane; i < CB; i += 64) {
    double v = (double)row[i];
    s += v * v;
  }
#pragma unroll
  for (int off = 32; off > 0; off >>= 1)
    s += __shfl_down(s, off, 64);
  if (lane == 0) { cnorm[gw] = s; cnormF[gw] = (float)s; }
}

// ---------------------------------------------------------------------------
// Encoder GEMM via v_mfma_f64_16x16x4 (matrix pipe). Runtime layout probe
// (verified R9: MfmaUtil 80%, passes with absmax 8.0).
// ---------------------------------------------------------------------------
__global__ __launch_bounds__(256, 4) void enc_gemm(
    const float* __restrict__ X, const float* __restrict__ W,
    const float* __restrict__ bias, float* __restrict__ R) {
  __shared__ double As[128][18];  // [m][kk], pad 18
  __shared__ double Bs[16][66];   // [kk][n], pad 66
  int tid = threadIdx.x;
  int wave = tid >> 6, lane = tid & 63;
  int q = lane >> 4, l15 = lane & 15;
  int g = blockIdx.x;
  int rb = (g & 7) + ((g >> 6) << 3);  // 8 col-blocks of rb share an XCD
  int cb8 = (g >> 3) & 7;
  int row0 = rb * 128, col0 = cb8 * 64;

  // --- layout probes ---
  f64x4 accP = (f64x4){0.0, 0.0, 0.0, 0.0};
  f64x4 accQ = (f64x4){0.0, 0.0, 0.0, 0.0};
  {
    double sel = (q == 0) ? 1.0 : 0.0;
    accP = __builtin_amdgcn_mfma_f64_16x16x4f64((double)l15, sel, accP, 0, 0, 0);
    accQ = __builtin_amdgcn_mfma_f64_16x16x4f64(sel, (double)l15, accQ, 0, 0, 0);
  }
  int rI[4], cI[4];
#pragma unroll
  for (int r = 0; r < 4; ++r) { rI[r] = (int)accP[r]; cI[r] = (int)accQ[r]; }

  int sm = tid >> 1, skb = (tid & 1) * 8;   // A staging: row, k-base
  int bkk = tid >> 4, bn = (tid & 15) * 4;  // B staging: kk, col

  f64x4 acc[2][4];
#pragma unroll
  for (int i = 0; i < 2; ++i)
#pragma unroll
    for (int j = 0; j < 4; ++j)
      acc[i][j] = (f64x4){0.0, 0.0, 0.0, 0.0};

  for (int k0 = 0; k0 < DIN; k0 += 16) {
    float4 x0 = *(const float4*)(X + (size_t)(row0 + sm) * DIN + k0 + skb);
    float4 x1 = *(const float4*)(X + (size_t)(row0 + sm) * DIN + k0 + skb + 4);
    float4 w0 = *(const float4*)(W + (size_t)(k0 + bkk) * CB + col0 + bn);
    __syncthreads();  // previous iteration's LDS reads done
    As[sm][skb + 0] = (double)x0.x; As[sm][skb + 1] = (double)x0.y;
    As[sm][skb + 2] = (double)x0.z; As[sm][skb + 3] = (double)x0.w;
    As[sm][skb + 4] = (double)x1.x; As[sm][skb + 5] = (double)x1.y;
    As[sm][skb + 6] = (double)x1.z; As[sm][skb + 7] = (double)x1.w;
    Bs[bkk][bn + 0] = (double)w0.x; Bs[bkk][bn + 1] = (double)w0.y;
    Bs[bkk][bn + 2] = (double)w0.z; Bs[bkk][bn + 3] = (double)w0.w;
    __syncthreads();
#pragma unroll
    for (int s = 0; s < 4; ++s) {
      int kk = s * 4 + q;
      double a0 = As[wave * 32 + l15][kk];
      double a1 = As[wave * 32 + 16 + l15][kk];
      double b0 = Bs[kk][l15];
      double b1 = Bs[kk][16 + l15];
      double b2 = Bs[kk][32 + l15];
      double b3 = Bs[kk][48 + l15];
      acc[0][0] = __builtin_amdgcn_mfma_f64_16x16x4f64(a0, b0, acc[0][0], 0, 0, 0);
      acc[0][1] = __builtin_amdgcn_mfma_f64_16x16x4f64(a0, b1, acc[0][1], 0, 0, 0);
      acc[0][2] = __builtin_amdgcn_mfma_f64_16x16x4f64(a0, b2, acc[0][2], 0, 0, 0);
      acc[0][3] = __builtin_amdgcn_mfma_f64_16x16x4f64(a0, b3, acc[0][3], 0, 0, 0);
      acc[1][0] = __builtin_amdgcn_mfma_f64_16x16x4f64(a1, b0, acc[1][0], 0, 0, 0);
      acc[1][1] = __builtin_amdgcn_mfma_f64_16x16x4f64(a1, b1, acc[1][1], 0, 0, 0);
      acc[1][2] = __builtin_amdgcn_mfma_f64_16x16x4f64(a1, b2, acc[1][2], 0, 0, 0);
      acc[1][3] = __builtin_amdgcn_mfma_f64_16x16x4f64(a1, b3, acc[1][3], 0, 0, 0);
    }
  }

  // Epilogue: scatter via probed (row, col) mapping. Scalar stores.
#pragma unroll
  for (int ti = 0; ti < 2; ++ti) {
#pragma unroll
    for (int tj = 0; tj < 4; ++tj) {
#pragma unroll
      for (int r = 0; r < 4; ++r) {
        int row = row0 + wave * 32 + ti * 16 + rI[r];
        int col = col0 + tj * 16 + cI[r];
        R[(size_t)row * CB + col] =
            (float)(acc[ti][tj][r] + (double)bias[col]);
      }
    }
  }
}

// ---------------------------------------------------------------------------
// Stage 1: 1-term fp16 MFMA distance GEMM, 128x128 tile, BK=32.
// S = fp16(R) . fp16(C), fp32 acc; d = cnormF - 2S; per-row top-2 per
// 128-col block -> cand. Staging: 2 matrices, 1KB contiguous loads.
// ---------------------------------------------------------------------------
__global__ __launch_bounds__(256) void vq_stage1(
    const unsigned short* __restrict__ Rh16,
    const unsigned short* __restrict__ Ch16,
    const float* __restrict__ cnormF, float4* __restrict__ cand) {
  __shared__ __align__(16) char lds[16384];  // A: 8KB, B: 8KB
  __shared__ float4 sRed[128][2];
  int tid = threadIdx.x;
  int wave = tid >> 6, lane = tid & 63;
  int wm = wave >> 1, wn = wave & 1;
  int q = lane >> 4, l15 = lane & 15;
  int g = blockIdx.x;
  int rb = (g & 7) + ((g >> 6) << 3);  // 8 col-blocks of rb share an XCD
  int cbk = (g >> 3) & 7;
  int row0 = rb * 128, n0 = cbk * 128;

  f32x4 acc[4][4];
#pragma unroll
  for (int i = 0; i < 4; ++i)
#pragma unroll
    for (int j = 0; j < 4; ++j)
      acc[i][j] = (f32x4){0.f, 0.f, 0.f, 0.f};

  // waves 0,1 stage Rh16 (groups s0..s0+3); waves 2,3 stage Ch16.
  const unsigned short* gsrc = (wave < 2) ? Rh16 : Ch16;
  int gbase = ((wave < 2) ? row0 : n0) >> 4;
  int s0 = (wave & 1) * 4;
  const unsigned short* gw =
      gsrc + (size_t)(gbase + s0) * 8192 + lane * 8;
  char* lbase = lds + ((wave < 2) ? 0 : 8192) + s0 * 1024;

  for (int kt = 0; kt < 16; ++kt) {
    __syncthreads();
#pragma unroll
    for (int s = 0; s < 4; ++s) {
      __builtin_amdgcn_global_load_lds(
          (const __attribute__((address_space(1))) void*)(gw + (size_t)s * 8192 + kt * 512),
          (__attribute__((address_space(3))) void*)(lbase + s * 1024), 16, 0, 0);
    }
    __syncthreads();

    half8 af[4];
#pragma unroll
    for (int ti = 0; ti < 4; ++ti)
      af[ti] = *(const half8*)(lds + (wm * 4 + ti) * 1024 + lane * 16);
#pragma unroll
    for (int tj = 0; tj < 4; ++tj) {
      half8 b = *(const half8*)(lds + 8192 + (wn * 4 + tj) * 1024 + lane * 16);
#pragma unroll
      for (int ti = 0; ti < 4; ++ti)
        acc[ti][tj] = __builtin_amdgcn_mfma_f32_16x16x32_f16(af[ti], b, acc[ti][tj], 0, 0, 0);
    }
  }

  // Epilogue: d = cn - 2S; per-row top-2 over this wave's 64 cols, then
  // cross-wn merge via sRed.
  float cn[4]; int coln[4];
#pragma unroll
  for (int tj = 0; tj < 4; ++tj) {
    coln[tj] = n0 + wn * 64 + tj * 16 + l15;
    cn[tj] = cnormF[coln[tj]];
  }
#pragma unroll
  for (int ti = 0; ti < 4; ++ti) {
#pragma unroll
    for (int r = 0; r < 4; ++r) {
      float m1 = FLT_MAX, m2 = FLT_MAX;
      int i1 = INT_MAX, i2 = INT_MAX;
#pragma unroll
      for (int tj = 0; tj < 4; ++tj) {
        float v = cn[tj] - 2.0f * acc[ti][tj][r];
        int ix = coln[tj];
        if (v < m1 || (v == m1 && ix < i1)) {
          m2 = m1; i2 = i1; m1 = v; i1 = ix;
        } else if (v < m2 || (v == m2 && ix < i2)) {
          m2 = v; i2 = ix;
        }
      }
#pragma unroll
      for (int mask = 1; mask <= 8; mask <<= 1) {
        float om1 = __shfl_xor(m1, mask, 64);
        int   oi1 = __shfl_xor(i1, mask, 64);
        float om2 = __shfl_xor(m2, mask, 64);
        int   oi2 = __shfl_xor(i2, mask, 64);
        if (om1 < m1 || (om1 == m1 && oi1 < i1)) {
          m2 = m1; i2 = i1; m1 = om1; i1 = oi1;
        } else if (om1 < m2 || (om1 == m2 && oi1 < i2)) {
          m2 = om1; i2 = oi1;
        }
        if (om2 < m1 || (om2 == m1 && oi2 < i1)) {
          m2 = m1; i2 = i1; m1 = om2; i1 = oi2;
        } else if (om2 < m2 || (om2 == m2 && oi2 < i2)) {
          m2 = om2; i2 = oi2;
        }
      }
      if (l15 == 0) {
        int rit = wm * 64 + ti * 16 + q * 4 + r;
        sRed[rit][wn] =
            make_float4(m1, __int_as_float(i1), m2, __int_as_float(i2));
      }
    }
  }
  __syncthreads();

  if (tid < 128) {
    float4 e0 = sRed[tid][0], e1 = sRed[tid][1];
    float v[4] = {e0.x, e0.z, e1.x, e1.z};
    int ix[4] = {__float_as_int(e0.y), __float_as_int(e0.w),
                 __float_as_int(e1.y), __float_as_int(e1.w)};
    float M1 = FLT_MAX, M2 = FLT_MAX;
    int I1 = INT_MAX, I2 = INT_MAX;
#pragma unroll
    for (int p = 0; p < 4; ++p) {
      if (v[p] < M1 || (v[p] == M1 && ix[p] < I1)) {
        M2 = M1; I2 = I1; M1 = v[p]; I1 = ix[p];
      } else if (v[p] < M2 || (v[p] == M2 && ix[p] < I2)) {
        M2 = v[p]; I2 = ix[p];
      }
    }
    cand[(size_t)(row0 + tid) * 8 + cbk] =
        make_float4(M1, __int_as_float(I1), M2, __int_as_float(I2));
  }
}

// ---------------------------------------------------------------------------
// Stage 2: combine 8 chunk top-2s; fp64-refine near-ties (vs fp32 R);
// write id; update residual (row-major R) + staged fp16 Rh16.
// ---------------------------------------------------------------------------
__global__ __launch_bounds__(256) void vq_refine(
    const float* __restrict__ cb, const double* __restrict__ cnorm,
    const float4* __restrict__ cand, float* __restrict__ R,
    unsigned short* __restrict__ Rh16, float* __restrict__ idsF, int layer) {
  __shared__ int sIdx[64][16];
  __shared__ int sCnt[64];
  __shared__ int sBest[64];

  int tid = threadIdx.x;
  int row0 = blockIdx.x * 64;

  if (tid < 64) {
    int row = row0 + tid;
    float v[16]; int ix[16];
#pragma unroll
    for (int c = 0; c < 8; ++c) {
      float4 e = cand[(size_t)row * 8 + c];
      v[2 * c] = e.x;     ix[2 * c] = __float_as_int(e.y);
      v[2 * c + 1] = e.z; ix[2 * c + 1] = __float_as_int(e.w);
    }
    float M = FLT_MAX; int I = INT_MAX;
#pragma unroll
    for (int p = 0; p < 16; ++p)
      if (v[p] < M || (v[p] == M && ix[p] < I)) { M = v[p]; I = ix[p]; }
    int cnt = 0;
#pragma unroll
    for (int p = 0; p < 16; ++p)
      if (v[p] < M + DELTA && cnt < 16) sIdx[tid][cnt++] = ix[p];
    sCnt[tid] = cnt;
    sBest[tid] = I;
  }
  __syncthreads();

  int wave = tid >> 6, lane = tid & 63;
  for (int r = wave * 16; r < wave * 16 + 16; ++r) {
    int cnt = sCnt[r];
    if (cnt < 2) continue;
    double bestD = 1e300; int bestI = INT_MAX;
    const float* rrow = R + (size_t)(row0 + r) * CB;
    for (int c = 0; c < cnt; ++c) {
      int idx = sIdx[r][c];
      const float* crow = cb + (size_t)idx * CB;
      double s = 0.0;
      for (int e = lane; e < CB; e += 64)
        s += (double)rrow[e] * (double)crow[e];
#pragma unroll
      for (int off = 32; off > 0; off >>= 1)
        s += __shfl_xor(s, off, 64);
      double d = cnorm[idx] - 2.0 * s;
      if (d < bestD || (d == bestD && idx < bestI)) { bestD = d; bestI = idx; }
    }
    if (lane == 0) sBest[r] = bestI;
  }
  __syncthreads();

  if (tid < 64)
    idsF[(size_t)(row0 + tid) * NL + layer] = (float)sBest[tid];

  // residual update: 4 elements per thread per iter
  for (int it = tid; it < 64 * (CB / 4); it += 256) {
    int r = it >> 7, dq = (it & 127) * 4;
    int row = row0 + r;
    size_t o = (size_t)row * CB + dq;
    float4 rv = *(const float4*)(R + o);
    const float* crow = cb + (size_t)sBest[r] * CB + dq;
    float nv[4] = {rv.x - crow[0], rv.y - crow[1], rv.z - crow[2], rv.w - crow[3]};
    *(float4*)(R + o) = make_float4(nv[0], nv[1], nv[2], nv[3]);
    size_t so = staged_off(row, dq);  // dq aligned 4 -> one chunk
    *(ushort4*)(Rh16 + so) =
        make_ushort4(f2h(nv[0]), f2h(nv[1]), f2h(nv[2]), f2h(nv[3]));
  }
}

// ---------------------------------------------------------------------------
// recon[b][j] = dec_b[j] + sum_l ids[b][l] * dec_W[l][j]
// ---------------------------------------------------------------------------
__global__ __launch_bounds__(256) void recon_kernel(
    const float* __restrict__ idsF, const float* __restrict__ decW,
    const float* __restrict__ decb, float* __restrict__ recon) {
  int g = blockIdx.x * 256 + threadIdx.x;
  int b = g >> 9, j = g & (CB - 1);
  float s = decb[j];
#pragma unroll
  for (int l = 0; l < NL; ++l)
    s += idsF[(size_t)b * NL + l] * decW[l * CB + j];
  recon[g] = s;
}

extern "C" void kernel_launch(void* const* d_in, const int* in_sizes, int n_in,
                              void* d_out, int out_size, void* d_ws, size_t ws_size,
                              hipStream_t stream) {
  const float* X    = (const float*)d_in[0];
  const float* encW = (const float*)d_in[1];
  const float* encb = (const float*)d_in[2];
  const float* cbs  = (const float*)d_in[3];
  const float* decW = (const float*)d_in[4];
  const float* decb = (const float*)d_in[5];

  float* out = (float*)d_out;
  float* recon = out;
  float* idsF = out + (size_t)BB * CB;

  char* ws = (char*)d_ws;
  float* R = (float*)ws;                     ws += (size_t)BB * CB * 4;        // 32 MB
  unsigned short* Rh16 = (unsigned short*)ws; ws += (size_t)BB * CB * 2;       // 16 MB
  unsigned short* Ch16 = (unsigned short*)ws; ws += (size_t)NL * KC * CB * 2;  // 4 MB
  double* cnorm = (double*)ws;               ws += (size_t)NL * KC * 8;        // 32 KB
  float* cnormF = (float*)ws;                ws += (size_t)NL * KC * 4;        // 16 KB
  float4* cand = (float4*)ws;                // [BB][8] float4 = 2 MB

  cbsplit_kernel<<<(NL * KC * CB) / 1024, 256, 0, stream>>>(cbs, Ch16);
  cnorm_kernel<<<(NL * KC) / 4, 256, 0, stream>>>(cbs, cnorm, cnormF);
  enc_gemm<<<(BB / 128) * (CB / 64), 256, 0, stream>>>(X, encW, encb, R);
  rsplit_kernel<<<(BB * CB) / 1024, 256, 0, stream>>>(R, Rh16);
  for (int l = 0; l < NL; ++l) {
    const float* cbl = cbs + (size_t)l * KC * CB;
    vq_stage1<<<(BB / 128) * 8, 256, 0, stream>>>(
        Rh16, Ch16 + (size_t)l * KC * CB, cnormF + (size_t)l * KC, cand);
    vq_refine<<<BB / 64, 256, 0, stream>>>(cbl, cnorm + (size_t)l * KC, cand,
                                           R, Rh16, idsF, l);
  }
  recon_kernel<<<(BB * CB) / 256, 256, 0, stream>>>(idsF, decW, decb, recon);
}